// Round 1
// baseline (348.297 us; speedup 1.0000x reference)
//
#include <hip/hip_runtime.h>

#define B_  8
#define K_  256
#define C_  8
#define PS  64
#define H_  512
#define W_  512
#define HW_ (H_ * W_)

// Detect whether coords buffer is int64 (little-endian lo/hi pairs, hi==0 since
// coords are small non-negative) or already int32; write decoded int32 coords.
__global__ void decode_coords_kernel(const int* __restrict__ raw,
                                     int* __restrict__ coords, int n) {
    __shared__ int s_nonzero;
    if (threadIdx.x == 0) s_nonzero = 0;
    __syncthreads();
    // Check odd int32 positions within the first n int32s (safe for both layouts:
    // buffer holds at least n int32s in either interpretation).
    int local = 0;
    for (int i = 2 * threadIdx.x + 1; i < n; i += 2 * blockDim.x) {
        if (raw[i] != 0) local = 1;
    }
    if (local) atomicOr(&s_nonzero, 1);
    __syncthreads();
    bool is64 = (s_nonzero == 0);  // all odd words zero -> int64 layout
    for (int i = threadIdx.x; i < n; i += blockDim.x) {
        coords[i] = is64 ? raw[2 * i] : raw[i];
    }
}

// One thread per (b, k, py, px): 8 channel loads + 8 out atomics + 1 cnt atomic.
__global__ void scatter_kernel(const float* __restrict__ logits,
                               const int* __restrict__ coords,
                               float* __restrict__ out,
                               float* __restrict__ cnt) {
    int i = blockIdx.x * blockDim.x + threadIdx.x;  // over B*K*PS*PS
    int px = i & (PS - 1);
    int py = (i >> 6) & (PS - 1);
    int k  = (i >> 12) & (K_ - 1);
    int b  = i >> 20;

    int r = coords[((b * K_ + k) << 1) + 0] + py;
    int c = coords[((b * K_ + k) << 1) + 1] + px;
    // Invalid positions contribute 0 to both out and cnt in the reference.
    if ((unsigned)r >= H_ || (unsigned)c >= W_) return;

    int hw = r * W_ + c;
    atomicAdd(&cnt[b * HW_ + hw], 1.0f);

    const float* src = logits + (((size_t)(b * K_ + k) * C_) << 12) + (py << 6) + px;
    float* dst = out + (size_t)b * C_ * HW_ + hw;
#pragma unroll
    for (int ch = 0; ch < C_; ++ch) {
        atomicAdd(dst + (size_t)ch * HW_, src[(size_t)ch << 12]);
    }
}

// One thread per (b, hw): normalize all 8 channels in place.
__global__ void finalize_kernel(float* __restrict__ out,
                                const float* __restrict__ cnt) {
    int i = blockIdx.x * blockDim.x + threadIdx.x;  // over B*HW
    float cv = cnt[i];
    bool covered = cv > 1e-6f;
    float inv = 1.0f / fmaxf(cv, 1e-6f);
    int b  = i >> 18;           // HW_ = 2^18
    int hw = i & (HW_ - 1);
    float* p = out + (size_t)b * C_ * HW_ + hw;
#pragma unroll
    for (int ch = 0; ch < C_; ++ch) {
        float v = p[(size_t)ch * HW_];
        p[(size_t)ch * HW_] = covered ? v * inv : -10.0f;
    }
}

extern "C" void kernel_launch(void* const* d_in, const int* in_sizes, int n_in,
                              void* d_out, int out_size, void* d_ws, size_t ws_size,
                              hipStream_t stream) {
    const float* logits = (const float*)d_in[0];
    const int* raw_coords = (const int*)d_in[1];
    float* out = (float*)d_out;

    int* coords = (int*)d_ws;                         // 16 KiB decoded coords
    float* cnt = (float*)((char*)d_ws + 16384);       // 8 MiB counts

    hipMemsetAsync(out, 0, (size_t)out_size * sizeof(float), stream);
    hipMemsetAsync(cnt, 0, (size_t)B_ * HW_ * sizeof(float), stream);

    decode_coords_kernel<<<1, 256, 0, stream>>>(raw_coords, coords, B_ * K_ * 2);

    int total = B_ * K_ * PS * PS;  // 8.4M threads
    scatter_kernel<<<total / 256, 256, 0, stream>>>(logits, coords, out, cnt);

    finalize_kernel<<<(B_ * HW_) / 256, 256, 0, stream>>>(out, cnt);
}

// Round 2
// 131.492 us; speedup vs baseline: 2.6488x; 2.6488x over previous
//
#include <hip/hip_runtime.h>

#define B_  8
#define K_  256
#define C_  8
#define PS  64
#define H_  512
#define W_  512
#define HW_ (H_ * W_)
#define TH  32
#define TW  32

// Detect whether coords buffer is int64 (little-endian lo/hi pairs, hi==0 since
// coords are small non-negative) or already int32; write decoded int32 coords.
__global__ void decode_coords_kernel(const int* __restrict__ raw,
                                     int* __restrict__ coords, int n) {
    __shared__ int s_nonzero;
    if (threadIdx.x == 0) s_nonzero = 0;
    __syncthreads();
    int local = 0;
    for (int i = 2 * threadIdx.x + 1; i < n; i += 2 * blockDim.x) {
        if (raw[i] != 0) local = 1;
    }
    if (local) atomicOr(&s_nonzero, 1);
    __syncthreads();
    bool is64 = (s_nonzero == 0);  // all odd words zero -> int64 layout
    for (int i = threadIdx.x; i < n; i += blockDim.x) {
        coords[i] = is64 ? raw[2 * i] : raw[i];
    }
}

// Gather: one block per 32x32 output tile of one batch. Each thread owns 4
// fixed pixels; accumulators live in registers; finalize fused. No atomics.
__global__ __launch_bounds__(256)
void gather_kernel(const float* __restrict__ logits,
                   const int* __restrict__ coords,
                   float* __restrict__ out) {
    const int b   = blockIdx.z;
    const int ty0 = blockIdx.y * TH;
    const int tx0 = blockIdx.x * TW;

    __shared__ int2 s_coords[K_];
    for (int k = threadIdx.x; k < K_; k += 256) {
        s_coords[k] = ((const int2*)coords)[b * K_ + k];
    }
    __syncthreads();

    float acc[4][C_];
    float cnt[4];
#pragma unroll
    for (int j = 0; j < 4; ++j) {
        cnt[j] = 0.0f;
#pragma unroll
        for (int ch = 0; ch < C_; ++ch) acc[j][ch] = 0.0f;
    }

    for (int k = 0; k < K_; ++k) {
        const int r = s_coords[k].x;
        const int c = s_coords[k].y;
        // Uniform tile-level overlap reject.
        if (r >= ty0 + TH || r + PS <= ty0 || c >= tx0 + TW || c + PS <= tx0)
            continue;
        const float* base = logits + (((size_t)(b * K_ + k)) << 15);  // *C*ps*ps
#pragma unroll
        for (int j = 0; j < 4; ++j) {
            const int p  = threadIdx.x + j * 256;
            const int py = ty0 + (p >> 5) - r;   // y within patch
            const int px = tx0 + (p & 31) - c;   // x within patch
            if ((unsigned)py < PS && (unsigned)px < PS) {
                const float* src = base + (py << 6) + px;
                cnt[j] += 1.0f;
#pragma unroll
                for (int ch = 0; ch < C_; ++ch) acc[j][ch] += src[(size_t)ch << 12];
            }
        }
    }

    // Fused finalize + store (each output pixel written exactly once).
#pragma unroll
    for (int j = 0; j < 4; ++j) {
        const int p = threadIdx.x + j * 256;
        const int y = ty0 + (p >> 5);
        const int x = tx0 + (p & 31);
        const bool covered = cnt[j] > 1e-6f;
        const float inv = 1.0f / fmaxf(cnt[j], 1e-6f);
#pragma unroll
        for (int ch = 0; ch < C_; ++ch) {
            const float v = covered ? acc[j][ch] * inv : -10.0f;
            out[(((size_t)(b * C_ + ch)) << 18) + y * W_ + x] = v;
        }
    }
}

extern "C" void kernel_launch(void* const* d_in, const int* in_sizes, int n_in,
                              void* d_out, int out_size, void* d_ws, size_t ws_size,
                              hipStream_t stream) {
    const float* logits = (const float*)d_in[0];
    const int* raw_coords = (const int*)d_in[1];
    float* out = (float*)d_out;

    int* coords = (int*)d_ws;  // 16 KiB decoded coords

    decode_coords_kernel<<<1, 256, 0, stream>>>(raw_coords, coords, B_ * K_ * 2);

    dim3 grid(W_ / TW, H_ / TH, B_);  // 16 x 16 x 8 = 2048 blocks
    gather_kernel<<<grid, 256, 0, stream>>>(logits, coords, out);
}